// Round 12
// baseline (82.061 us; speedup 1.0000x reference)
//
#include <hip/hip_runtime.h>

#define N_RAYS        131072
#define MAX_STEPS     128

// Identity barrier: forces the value through a VGPR via empty inline asm.
__device__ __forceinline__ float opq(float x) { asm("" : "+v"(x)); return x; }

// Correctly-rounded f32 divide, immune to fast-math rcp lowering.
__device__ __forceinline__ float fdiv_strict(float a, float b) {
    double q = (double)a / (double)b;
    return opq((float)q);
}

__global__ __launch_bounds__(256) void renderer_kernel(
    const float* __restrict__ raysO,
    const float* __restrict__ raysD,
    const float* __restrict__ grid,
    float* __restrict__ out)
{
    #pragma clang fp contract(off)

    const int i = blockIdx.x * blockDim.x + threadIdx.x;
    if (i >= N_RAYS) return;

    const float ox = raysO[3*i+0], oy = raysO[3*i+1], oz = raysO[3*i+2];
    const float dx = raysD[3*i+0], dy = raysD[3*i+1], dz = raysD[3*i+2];

    // ---- slab: strict f32, recip-mult form, CR divide (best-scoring: 24q) ----
    const float sdx = (fabsf(dx) > 1e-8f) ? dx : 1e-8f;
    const float sdy = (fabsf(dy) > 1e-8f) ? dy : 1e-8f;
    const float sdz = (fabsf(dz) > 1e-8f) ? dz : 1e-8f;
    const float rdx = fdiv_strict(1.0f, sdx);
    const float rdy = fdiv_strict(1.0f, sdy);
    const float rdz = fdiv_strict(1.0f, sdz);
    const float t0x = opq(opq(-2.0f - ox) * rdx);
    const float t1x = opq(opq( 2.0f - ox) * rdx);
    const float t0y = opq(opq(-2.0f - oy) * rdy);
    const float t1y = opq(opq( 2.0f - oy) * rdy);
    const float t0z = opq(opq(-2.0f - oz) * rdz);
    const float t1z = opq(opq( 2.0f - oz) * rdz);
    const float tmin = fmaxf(fmaxf(fminf(t0x, t1x), fminf(t0y, t1y)), fminf(t0z, t1z));
    const float tmax = fminf(fminf(fmaxf(t0x, t1x), fmaxf(t0y, t1y)), fmaxf(t0z, t1z));
    const float nearT = fmaxf(tmin, 0.05f);
    const float farT  = fmaxf(tmax, opq(nearT + 1e-6f));
    const float dtv   = opq(opq(farT - nearT) * 0.0078125f);   // /128: pow2-exact

    float T = 1.0f;
    float accR = 0.0f, accG = 0.0f, accB = 0.0f;
    float wsum = 0.0f;

    for (int s = 0; s < MAX_STEPS; ++s) {
        // t: FUSED single-rounding (the last untested cell of the factorial)
        const float sp = opq((float)s + 0.5f);               // exact
        const float t  = opq(__builtin_fmaf(sp, dtv, nearT));
        // xyz: strict two-rounding
        const float x  = opq(ox + opq(t * dx));
        const float y  = opq(oy + opq(t * dy));
        const float z  = opq(oz + opq(t * dz));

        // cascade: clip(ceil(log2(max(mx,1))), 0, 1) == (mx > 1)   (exact)
        const float mx = fmaxf(fmaxf(fabsf(x), fabsf(y)), fabsf(z));
        const int   cas = (mx > 1.0f) ? 1 : 0;
        const float hib = (mx > 1.0f) ? 0.25f : 0.5f;        // pow2-exact

        const float ux = fminf(fmaxf(opq(opq(x * hib) + 0.5f), 0.0f), 1.0f - 1e-6f);
        const float uy = fminf(fmaxf(opq(opq(y * hib) + 0.5f), 0.0f), 1.0f - 1e-6f);
        const float uz = fminf(fmaxf(opq(opq(z * hib) + 0.5f), 0.0f), 1.0f - 1e-6f);
        const int ix = (int)opq(ux * 128.0f);                // pow2-exact
        const int iy = (int)opq(uy * 128.0f);
        const int iz = (int)opq(uz * 128.0f);

        const int gi = (cas << 21) + (ix << 14) + (iy << 7) + iz;
        const float gv = grid[gi];

        if (gv > 10.0f) {                                    // exact compare
            const float d2    = x * x + y * y + z * z;
            const float sigma = 5.0f * expf(-(d2 / 0.08f));
            const float alpha = 1.0f - expf(-(sigma * dtv));
            const float w     = alpha * T;

            const float cr = fminf(fmaxf(x * 0.25f + 0.5f, 0.0f), 1.0f);
            const float cg = fminf(fmaxf(y * 0.25f + 0.5f, 0.0f), 1.0f);
            const float cb = fminf(fmaxf(z * 0.25f + 0.5f, 0.0f), 1.0f);

            accR += w * cr;
            accG += w * cg;
            accB += w * cb;
            wsum += w;
            T *= (1.0f - alpha);
        }
    }

    const float bg = 1.0f - wsum;   // bgColor = 1
    out[3*i+0] = accR + bg;
    out[3*i+1] = accG + bg;
    out[3*i+2] = accB + bg;
}

extern "C" void kernel_launch(void* const* d_in, const int* in_sizes, int n_in,
                              void* d_out, int out_size, void* d_ws, size_t ws_size,
                              hipStream_t stream) {
    const float* raysO = (const float*)d_in[0];
    const float* raysD = (const float*)d_in[1];
    const float* grid  = (const float*)d_in[2];
    float* out = (float*)d_out;

    const int threads = 256;
    const int blocks  = (N_RAYS + threads - 1) / threads;   // 512
    renderer_kernel<<<blocks, threads, 0, stream>>>(raysO, raysD, grid, out);
}

// Round 13
// 43.077 us; speedup vs baseline: 1.9050x; 1.9050x over previous
//
#include <hip/hip_runtime.h>

#define N_RAYS        131072
#define MAX_STEPS     128

// Identity barrier: forces the value through a VGPR via empty inline asm.
__device__ __forceinline__ float opq(float x) { asm("" : "+v"(x)); return x; }

// Correctly-rounded f32 divide, immune to fast-math rcp lowering.
__device__ __forceinline__ float fdiv_strict(float a, float b) {
    double q = (double)a / (double)b;
    return opq((float)q);
}

__global__ __launch_bounds__(256) void renderer_kernel(
    const float* __restrict__ raysO,
    const float* __restrict__ raysD,
    const float* __restrict__ grid,
    float* __restrict__ out)
{
    #pragma clang fp contract(off)

    const int i = blockIdx.x * blockDim.x + threadIdx.x;
    if (i >= N_RAYS) return;

    const float ox = raysO[3*i+0], oy = raysO[3*i+1], oz = raysO[3*i+2];
    const float dx = raysD[3*i+0], dy = raysD[3*i+1], dz = raysD[3*i+2];

    // ---- slab: strict f32, recip-mult form, CR divide (verified R12) ----
    const float sdx = (fabsf(dx) > 1e-8f) ? dx : 1e-8f;
    const float sdy = (fabsf(dy) > 1e-8f) ? dy : 1e-8f;
    const float sdz = (fabsf(dz) > 1e-8f) ? dz : 1e-8f;
    const float rdx = fdiv_strict(1.0f, sdx);
    const float rdy = fdiv_strict(1.0f, sdy);
    const float rdz = fdiv_strict(1.0f, sdz);
    const float t0x = opq(opq(-2.0f - ox) * rdx);
    const float t1x = opq(opq( 2.0f - ox) * rdx);
    const float t0y = opq(opq(-2.0f - oy) * rdy);
    const float t1y = opq(opq( 2.0f - oy) * rdy);
    const float t0z = opq(opq(-2.0f - oz) * rdz);
    const float t1z = opq(opq( 2.0f - oz) * rdz);
    const float tmin = fmaxf(fmaxf(fminf(t0x, t1x), fminf(t0y, t1y)), fminf(t0z, t1z));
    const float tmax = fminf(fminf(fmaxf(t0x, t1x), fmaxf(t0y, t1y)), fmaxf(t0z, t1z));
    const float nearT = fmaxf(tmin, 0.05f);
    const float farT  = fmaxf(tmax, opq(nearT + 1e-6f));
    const float dtv   = opq(opq(farT - nearT) * 0.0078125f);   // /128: pow2-exact

    // ---- blob culling: sigma(d2>0.9) <= 2.3e-4; skipping those steps adds
    // <= 128*dt_max*5*exp(-0.9/0.08) ~ 4.5e-4 per channel. Ray-sphere window
    // (unit-norm d), widened by sqrt margin + 1 step each side. ----
    int s_lo = 0, s_hi = -1;                                   // default: empty
    {
        const float b    = ox*dx + oy*dy + oz*dz;
        const float c    = ox*ox + oy*oy + oz*oz - 0.9f;
        const float disc = b*b - c;
        if (disc > 0.0f) {
            const float sq = sqrtf(disc) + 0.01f;              // conservative
            const float inv_dt = 1.0f / dtv;
            float fs_lo = (-b - sq - nearT) * inv_dt - 0.5f;
            float fs_hi = (-b + sq - nearT) * inv_dt - 0.5f;
            fs_lo = fminf(fmaxf(fs_lo, -2.0f), 130.0f);        // safe int range
            fs_hi = fminf(fmaxf(fs_hi, -2.0f), 130.0f);
            s_lo = max(0, (int)floorf(fs_lo) - 1);
            s_hi = min(MAX_STEPS - 1, (int)ceilf(fs_hi) + 1);
        }
    }

    float T = 1.0f;
    float accR = 0.0f, accG = 0.0f, accB = 0.0f;
    float wsum = 0.0f;

    for (int s = s_lo; s <= s_hi; ++s) {
        // ---- verified per-step chain (bit-identical to the R12 pass) ----
        const float sp = opq((float)s + 0.5f);                 // exact
        const float t  = opq(__builtin_fmaf(sp, dtv, nearT));  // fused (verified)
        const float x  = opq(ox + opq(t * dx));                // strict 2-rounding
        const float y  = opq(oy + opq(t * dy));
        const float z  = opq(oz + opq(t * dz));

        const float mx = fmaxf(fmaxf(fabsf(x), fabsf(y)), fabsf(z));
        const int   cas = (mx > 1.0f) ? 1 : 0;
        const float hib = (mx > 1.0f) ? 0.25f : 0.5f;          // pow2-exact

        const float ux = fminf(fmaxf(opq(opq(x * hib) + 0.5f), 0.0f), 1.0f - 1e-6f);
        const float uy = fminf(fmaxf(opq(opq(y * hib) + 0.5f), 0.0f), 1.0f - 1e-6f);
        const float uz = fminf(fmaxf(opq(opq(z * hib) + 0.5f), 0.0f), 1.0f - 1e-6f);
        const int ix = (int)opq(ux * 128.0f);                  // pow2-exact
        const int iy = (int)opq(uy * 128.0f);
        const int iz = (int)opq(uz * 128.0f);

        const int gi = (cas << 21) + (ix << 14) + (iy << 7) + iz;
        const float gv = grid[gi];

        if (gv > 10.0f) {
            const float d2    = x * x + y * y + z * z;
            const float sigma = 5.0f * expf(-(d2 / 0.08f));
            const float alpha = 1.0f - expf(-(sigma * dtv));
            const float w     = alpha * T;

            const float cr = fminf(fmaxf(x * 0.25f + 0.5f, 0.0f), 1.0f);
            const float cg = fminf(fmaxf(y * 0.25f + 0.5f, 0.0f), 1.0f);
            const float cb = fminf(fmaxf(z * 0.25f + 0.5f, 0.0f), 1.0f);

            accR += w * cr;
            accG += w * cg;
            accB += w * cb;
            wsum += w;
            T *= (1.0f - alpha);
        }
    }

    const float bg = 1.0f - wsum;   // bgColor = 1
    out[3*i+0] = accR + bg;
    out[3*i+1] = accG + bg;
    out[3*i+2] = accB + bg;
}

extern "C" void kernel_launch(void* const* d_in, const int* in_sizes, int n_in,
                              void* d_out, int out_size, void* d_ws, size_t ws_size,
                              hipStream_t stream) {
    const float* raysO = (const float*)d_in[0];
    const float* raysD = (const float*)d_in[1];
    const float* grid  = (const float*)d_in[2];
    float* out = (float*)d_out;

    const int threads = 256;
    const int blocks  = (N_RAYS + threads - 1) / threads;   // 512
    renderer_kernel<<<blocks, threads, 0, stream>>>(raysO, raysD, grid, out);
}

// Round 14
// 29.202 us; speedup vs baseline: 2.8101x; 1.4751x over previous
//
#include <hip/hip_runtime.h>

#define N_RAYS        131072
#define MAX_STEPS     128

// Identity barrier: forces the value through a VGPR via empty inline asm.
__device__ __forceinline__ float opq(float x) { asm("" : "+v"(x)); return x; }

// Correctly-rounded f32 divide, immune to fast-math rcp lowering.
__device__ __forceinline__ float fdiv_strict(float a, float b) {
    double q = (double)a / (double)b;
    return opq((float)q);
}

__global__ __launch_bounds__(256) void renderer_kernel(
    const float* __restrict__ raysO,
    const float* __restrict__ raysD,
    const float* __restrict__ grid,
    float* __restrict__ out)
{
    #pragma clang fp contract(off)

    const int tid = blockIdx.x * blockDim.x + threadIdx.x;
    const int r   = tid >> 2;          // ray index
    const int seg = tid & 3;           // segment 0..3
    if (r >= N_RAYS) return;

    const float ox = raysO[3*r+0], oy = raysO[3*r+1], oz = raysO[3*r+2];
    const float dx = raysD[3*r+0], dy = raysD[3*r+1], dz = raysD[3*r+2];

    // ---- slab: strict f32, recip-mult form, CR divide (verified R12) ----
    const float sdx = (fabsf(dx) > 1e-8f) ? dx : 1e-8f;
    const float sdy = (fabsf(dy) > 1e-8f) ? dy : 1e-8f;
    const float sdz = (fabsf(dz) > 1e-8f) ? dz : 1e-8f;
    const float rdx = fdiv_strict(1.0f, sdx);
    const float rdy = fdiv_strict(1.0f, sdy);
    const float rdz = fdiv_strict(1.0f, sdz);
    const float t0x = opq(opq(-2.0f - ox) * rdx);
    const float t1x = opq(opq( 2.0f - ox) * rdx);
    const float t0y = opq(opq(-2.0f - oy) * rdy);
    const float t1y = opq(opq( 2.0f - oy) * rdy);
    const float t0z = opq(opq(-2.0f - oz) * rdz);
    const float t1z = opq(opq( 2.0f - oz) * rdz);
    const float tmin = fmaxf(fmaxf(fminf(t0x, t1x), fminf(t0y, t1y)), fminf(t0z, t1z));
    const float tmax = fminf(fminf(fmaxf(t0x, t1x), fmaxf(t0y, t1y)), fmaxf(t0z, t1z));
    const float nearT = fmaxf(tmin, 0.05f);
    const float farT  = fmaxf(tmax, opq(nearT + 1e-6f));
    const float dtv   = opq(opq(farT - nearT) * 0.0078125f);   // /128: pow2-exact

    // ---- blob culling (verified R13): sigma(d2>0.9) negligible ----
    int s_lo = 0, s_hi = -1;
    {
        const float b    = ox*dx + oy*dy + oz*dz;
        const float c    = ox*ox + oy*oy + oz*oz - 0.9f;
        const float disc = b*b - c;
        if (disc > 0.0f) {
            const float sq = sqrtf(disc) + 0.01f;
            const float inv_dt = 1.0f / dtv;
            float fs_lo = (-b - sq - nearT) * inv_dt - 0.5f;
            float fs_hi = (-b + sq - nearT) * inv_dt - 0.5f;
            fs_lo = fminf(fmaxf(fs_lo, -2.0f), 130.0f);
            fs_hi = fminf(fmaxf(fs_hi, -2.0f), 130.0f);
            s_lo = max(0, (int)floorf(fs_lo) - 1);
            s_hi = min(MAX_STEPS - 1, (int)ceilf(fs_hi) + 1);
        }
    }

    float T = 1.0f;
    float accR = 0.0f, accG = 0.0f, accB = 0.0f;
    float wsum = 0.0f;

    // ---- this thread's segment of the window ----
    const int n = s_hi - s_lo + 1;
    if (n > 0) {
        const int per = (n + 3) >> 2;
        const int lo  = s_lo + seg * per;
        const int hi  = min(lo + per - 1, s_hi);

        for (int s = lo; s <= hi; ++s) {
            // ---- verified per-step chain (bit-identical to R12 pass) ----
            const float sp = opq((float)s + 0.5f);                 // exact
            const float t  = opq(__builtin_fmaf(sp, dtv, nearT));  // fused
            const float x  = opq(ox + opq(t * dx));                // strict
            const float y  = opq(oy + opq(t * dy));
            const float z  = opq(oz + opq(t * dz));

            const float mx = fmaxf(fmaxf(fabsf(x), fabsf(y)), fabsf(z));
            const int   cas = (mx > 1.0f) ? 1 : 0;
            const float hib = (mx > 1.0f) ? 0.25f : 0.5f;          // pow2-exact

            const float ux = fminf(fmaxf(opq(opq(x * hib) + 0.5f), 0.0f), 1.0f - 1e-6f);
            const float uy = fminf(fmaxf(opq(opq(y * hib) + 0.5f), 0.0f), 1.0f - 1e-6f);
            const float uz = fminf(fmaxf(opq(opq(z * hib) + 0.5f), 0.0f), 1.0f - 1e-6f);
            const int ixv = (int)opq(ux * 128.0f);                 // pow2-exact
            const int iyv = (int)opq(uy * 128.0f);
            const int izv = (int)opq(uz * 128.0f);

            const int gi = (cas << 21) + (ixv << 14) + (iyv << 7) + izv;
            const float gv = grid[gi];

            if (gv > 10.0f) {
                const float d2    = x * x + y * y + z * z;
                const float sigma = 5.0f * expf(-(d2 / 0.08f));
                const float alpha = 1.0f - expf(-(sigma * dtv));
                const float w     = alpha * T;

                const float cr = fminf(fmaxf(x * 0.25f + 0.5f, 0.0f), 1.0f);
                const float cg = fminf(fmaxf(y * 0.25f + 0.5f, 0.0f), 1.0f);
                const float cb = fminf(fmaxf(z * 0.25f + 0.5f, 0.0f), 1.0f);

                accR += w * cr;
                accG += w * cg;
                accB += w * cb;
                wsum += w;
                T *= (1.0f - alpha);
            }
        }
    }

    // ---- ordered associative combine across the 4 segment lanes ----
    // (T_a,A_a) o (T_b,A_b) = (T_a*T_b, A_a + T_a*A_b); continuous rounding only.
    const int lane = threadIdx.x & 63;
    #pragma unroll
    for (int m = 1; m <= 2; m <<= 1) {
        const float To  = __shfl_xor(T,    m);
        const float aRo = __shfl_xor(accR, m);
        const float aGo = __shfl_xor(accG, m);
        const float aBo = __shfl_xor(accB, m);
        const float wo  = __shfl_xor(wsum, m);
        const bool left = ((lane & m) == 0);      // self is first part
        const float Tf  = left ? T    : To;       // first T
        const float aR1 = left ? accR : aRo, aR2 = left ? aRo : accR;
        const float aG1 = left ? accG : aGo, aG2 = left ? aGo : accG;
        const float aB1 = left ? accB : aBo, aB2 = left ? aBo : accB;
        const float w1  = left ? wsum : wo,  w2  = left ? wo  : wsum;
        accR = aR1 + Tf * aR2;
        accG = aG1 + Tf * aG2;
        accB = aB1 + Tf * aB2;
        wsum = w1  + Tf * w2;
        T    = T * To;
    }

    if (seg == 0) {
        const float bg = 1.0f - wsum;   // bgColor = 1
        out[3*r+0] = accR + bg;
        out[3*r+1] = accG + bg;
        out[3*r+2] = accB + bg;
    }
}

extern "C" void kernel_launch(void* const* d_in, const int* in_sizes, int n_in,
                              void* d_out, int out_size, void* d_ws, size_t ws_size,
                              hipStream_t stream) {
    const float* raysO = (const float*)d_in[0];
    const float* raysD = (const float*)d_in[1];
    const float* grid  = (const float*)d_in[2];
    float* out = (float*)d_out;

    const int threads = 256;
    const int total   = N_RAYS * 4;                      // 4 segments per ray
    const int blocks  = (total + threads - 1) / threads; // 2048
    renderer_kernel<<<blocks, threads, 0, stream>>>(raysO, raysD, grid, out);
}